// Round 13
// baseline (191.844 us; speedup 1.0000x reference)
//
#include <hip/hip_runtime.h>
#include <hip/hip_bf16.h>
#include <math.h>

#define BB 16
#define COUTC 64
#define HH 256
#define WWD 256
#define PW 260                // padded width/height (pad=2 each side)
#define NBLK (BB*HH)          // 4096 rows total
#define NBLK2 2048            // K1 grid: each block does 2 rows
#define NBLKW (NBLK*4)        // 16384 per-wave-row stat slots
#define NPIX (BB*HH*WWD)      // 1,048,576 pixels
#define YTOT ((size_t)NPIX*COUTC)   // 67,108,864 y elements

typedef __attribute__((ext_vector_type(8))) short short8;
typedef __attribute__((ext_vector_type(4))) float f32x4;
typedef __attribute__((ext_vector_type(4))) unsigned short us4;
typedef __attribute__((ext_vector_type(8))) unsigned short us8;

__device__ __forceinline__ unsigned short f2bf(float f) {
    __hip_bfloat16 h = __float2bfloat16(f);
    return __builtin_bit_cast(unsigned short, h);
}
__device__ __forceinline__ float bf2f(unsigned short u) {
    unsigned v = (unsigned)u << 16;
    return __builtin_bit_cast(float, v);
}

// ---------------------------------------------------------------------------
// Pre-pass 1: x NCHW fp32 -> zero-padded NHWC bf16  xp[b][y+2][x+2][4].
// ---------------------------------------------------------------------------
__global__ __launch_bounds__(256) void prep_kernel(
    const float* __restrict__ x,
    us4* __restrict__ xp)
{
    const int b  = blockIdx.x / PW;
    const int yr = blockIdx.x % PW - 2;          // y in [-2,257]
    const bool rok = (yr >= 0) && (yr < HH);
    const float* xb = x + (size_t)b * (3*HH*WWD) + (size_t)(rok ? yr : 0)*WWD;
    for (int cx = threadIdx.x; cx < PW; cx += 256) {
        const int xx = cx - 2;
        const bool ok = rok && (xx >= 0) && (xx < WWD);
        float f0 = ok ? xb[0*(HH*WWD) + xx] : 0.f;
        float f1 = ok ? xb[1*(HH*WWD) + xx] : 0.f;
        float f2 = ok ? xb[2*(HH*WWD) + xx] : 0.f;
        us4 v = { f2bf(f0), f2bf(f1), f2bf(f2), 0 };
        xp[((size_t)b*PW + (yr+2))*PW + cx] = v;
    }
}

// ---------------------------------------------------------------------------
// Pre-pass 2: B-fragment tables (pre-swizzled to MFMA layout, L2-hot):
//   wTg[512]: kc 0..3 = w_conv (k0..31), 4..7 = w_dcn (k32..63); [kc][n] us8
//   wOg[128]: offset-conv weights, [nt2][lane] us8
// ---------------------------------------------------------------------------
__global__ __launch_bounds__(256) void wtg_kernel(
    const float* __restrict__ w_dcn,
    const float* __restrict__ w_conv,
    const float* __restrict__ w_off,
    unsigned short* __restrict__ wTg,
    unsigned short* __restrict__ wOg)
{
    for (int e = threadIdx.x; e < 512; e += 256) {
        const int kc = e >> 6, n = e & 63;
        const float* wsrc = (kc < 4) ? w_conv : w_dcn;
        const int kb = (kc & 3) * 8;
        us8 v;
        #pragma unroll
        for (int j = 0; j < 8; ++j) {
            int kk = kb + j;
            v[j] = (kk < 27) ? f2bf(wsrc[n*27 + kk]) : (unsigned short)0;
        }
        *(us8*)(wTg + e*8) = v;
    }
    if (threadIdx.x < 128) {
        const int e = threadIdx.x;
        const int nt2 = e >> 6, l = e & 63;
        const int n = nt2*16 + (l & 15);
        const int kb = (l >> 4) * 8;
        us8 v;
        #pragma unroll
        for (int j = 0; j < 8; ++j) {
            int kk = kb + j;
            v[j] = (n < 18 && kk < 27) ? f2bf(w_off[n*27 + kk]) : (unsigned short)0;
        }
        *(us8*)(wOg + e*8) = v;
    }
}

// xn rows: cells (w+1..w+3) per row -> one dwordx4 (dx 0,1) + one dwordx2 (dx 2)
__device__ __forceinline__ void load_xn3(const us4* __restrict__ xpb, int h, int w,
                                         us8 r8[3], us4 r4[3])
{
    #pragma unroll
    for (int dy = 0; dy < 3; ++dy) {
        const us4* p = xpb + (size_t)(h+1+dy)*PW + (w+1);
        r8[dy] = *(const us8*)p;
        r4[dy] = p[2];
    }
}

// ---------------------------------------------------------------------------
// Kernel 1 (wave-autonomous, zero barriers, 2 rows/block software-pipelined):
// per row: pack xn -> offset conv on MFMA -> off via LDS scratch ->
// [issue NEXT row's xn loads] -> taps (2 x dwordx4 each) -> pack -> 32 MFMA
// -> register epilogue. Weights loaded once per block.
// K-layout: k0..26 = xn (pairs w_conv), k32..58 = taps (pairs w_dcn).
// ---------------------------------------------------------------------------
template<bool BF16Y>
__global__ __launch_bounds__(256, 3) void dcn_wave_kernel(
    const float* __restrict__ x,          // exact fallback only
    const us4* __restrict__ xp,
    const unsigned short* __restrict__ wTg,
    const unsigned short* __restrict__ wOg,
    const float* __restrict__ b_off,
    const float* __restrict__ b_conv,
    float* __restrict__ outf,
    unsigned short* __restrict__ yws,
    float* __restrict__ psum,     // [64][NBLKW]
    float* __restrict__ psq)      // [64][NBLKW]
{
    __shared__ __align__(16) char kbuf[32768];              // 4 x 8KB A-tiles
    __shared__ __align__(16) unsigned short sofs[4*64*24];  // 4 x 3KB scratch

    const int tid = threadIdx.x;
    const int bid = blockIdx.x;
    const int w = tid;
    const int l   = tid & 63;
    const int wv  = tid >> 6;
    const int g   = l >> 4;
    const int r15 = l & 15;
    char* kw = kbuf + wv*8192;
    unsigned short* so = sofs + wv*64*24;

    // --- loop-invariant weight fragments (once per block, L2-hot) ---------
    short8 bfr[2][4];
    #pragma unroll
    for (int ks = 0; ks < 2; ++ks)
        #pragma unroll
        for (int nt = 0; nt < 4; ++nt) {
            const int kc = ks*4 + g, n = nt*16 + r15;
            bfr[ks][nt] = *(const short8*)(wTg + (kc*64 + n)*8);
        }
    short8 wof[2];
    #pragma unroll
    for (int nt2 = 0; nt2 < 2; ++nt2)
        wof[nt2] = *(const short8*)(wOg + (nt2*64 + l)*8);

    // --- iteration 0 ids + xn preload -------------------------------------
    int eff = bid;
    int swz = ((eff & 7) << 9) | (eff >> 3);     // XCD-bijective over 4096
    int b = swz >> 8, h = swz & 255;
    const us4* xpb = xp + (size_t)b*PW*PW;
    us8 c8v[3]; us4 c4v[3];
    load_xn3(xpb, h, w, c8v, c4v);

    #pragma unroll
    for (int it = 0; it < 2; ++it) {
        // next-row ids (used only when it==0)
        const int eff_n = eff + NBLK2;
        const int swz_n = ((eff_n & 7) << 9) | ((eff_n >> 3) & 511);
        const int b_n = swz_n >> 8, h_n = swz_n & 255;
        const us4* xpb_n = xp + (size_t)b_n*PW*PW;

        // --- pack xn half (bits already bf16) -> chunks 0..3 --------------
        {
            unsigned short u[32];
            #pragma unroll
            for (int c = 0; c < 3; ++c)
                #pragma unroll
                for (int ky = 0; ky < 3; ++ky)
                    #pragma unroll
                    for (int kx = 0; kx < 3; ++kx)
                        u[c*9 + ky*3 + kx] = (kx == 2) ? c4v[ky][c]
                                                       : c8v[ky][kx*4 + c];
            #pragma unroll
            for (int k = 27; k < 32; ++k) u[k] = 0;
            #pragma unroll
            for (int c8 = 0; c8 < 4; ++c8) {
                uint4 v;
                v.x = (unsigned)u[c8*8+0] | ((unsigned)u[c8*8+1] << 16);
                v.y = (unsigned)u[c8*8+2] | ((unsigned)u[c8*8+3] << 16);
                v.z = (unsigned)u[c8*8+4] | ((unsigned)u[c8*8+5] << 16);
                v.w = (unsigned)u[c8*8+6] | ((unsigned)u[c8*8+7] << 16);
                *(uint4*)(kw + l*128 + ((c8 ^ (l & 7)) << 4)) = v;
            }
        }

        // --- offset conv on MFMA (af0 read, dies into dacc) ---------------
        f32x4 dacc[4][2];
        {
            short8 af0[4];
            #pragma unroll
            for (int mt = 0; mt < 4; ++mt) {
                int row = mt*16 + r15;
                af0[mt] = *(const short8*)(kw + row*128 + ((g ^ (row & 7)) << 4));
            }
            #pragma unroll
            for (int mt = 0; mt < 4; ++mt)
                #pragma unroll
                for (int nt2 = 0; nt2 < 2; ++nt2) {
                    dacc[mt][nt2] = (f32x4){0.f, 0.f, 0.f, 0.f};
                    dacc[mt][nt2] = __builtin_amdgcn_mfma_f32_16x16x32_bf16(
                        af0[mt], wof[nt2], dacc[mt][nt2], 0, 0, 0);
                }
        }

        // --- redistribute D -> per-pixel off[18] via LDS scratch ----------
        #pragma unroll
        for (int mt = 0; mt < 4; ++mt)
            #pragma unroll
            for (int nt2 = 0; nt2 < 2; ++nt2) {
                if (nt2 == 1 && r15 >= 2) continue;   // ch 18..31 unused
                #pragma unroll
                for (int r = 0; r < 4; ++r)
                    so[(mt*16 + g*4 + r)*24 + nt2*16 + r15] = f2bf(dacc[mt][nt2][r]);
            }

        // --- PREFETCH next row's xn (address-independent, hides under taps)
        us8 n8[3]; us4 n4[3];
        if (it == 0) load_xn3(xpb_n, h_n, w, n8, n4);

        float off[18];
        {
            us8 o0 = *(const us8*)(so + l*24);
            us8 o1 = *(const us8*)(so + l*24 + 8);
            us4 o2 = *(const us4*)(so + l*24 + 16);
            #pragma unroll
            for (int j = 0; j < 8; ++j)  off[j]   = bf2f(o0[j]) + b_off[j];
            #pragma unroll
            for (int j = 0; j < 8; ++j)  off[8+j] = bf2f(o1[j]) + b_off[8+j];
            off[16] = bf2f(o2[0]) + b_off[16];
            off[17] = bf2f(o2[1]) + b_off[17];
        }

        // --- taps: 2 x dwordx4 per tap (row pairs) ------------------------
        unsigned short ut[32];
        #pragma unroll
        for (int k = 0; k < 9; ++k) {
            const int ky = k / 3, kx = k % 3;
            float py = (float)(h + ky - 1) + off[2*k];
            float px = (float)(w + kx - 1) + off[2*k + 1];
            float y0f = floorf(py), x0f = floorf(px);
            float ly = py - y0f, lx = px - x0f;
            float hy = 1.f - ly, hx = 1.f - lx;
            int y0 = (int)y0f, x0 = (int)x0f;
            float t0, t1, t2;

            if (__builtin_expect(y0 >= -2 && y0 <= 256 && x0 >= -2 && x0 <= 256, 1)) {
                const us4* p0 = xpb + (size_t)(y0+2)*PW + (x0+2);
                us8 r0 = *(const us8*)p0;        // corners (y0,x0),(y0,x0+1)
                us8 r1 = *(const us8*)(p0 + PW); // corners (y0+1,x0),(y0+1,x0+1)
                float w00 = hy*hx, w01 = hy*lx, w10 = ly*hx, w11 = ly*lx;
                t0 = w00*bf2f(r0[0]) + w01*bf2f(r0[4]) + w10*bf2f(r1[0]) + w11*bf2f(r1[4]);
                t1 = w00*bf2f(r0[1]) + w01*bf2f(r0[5]) + w10*bf2f(r1[1]) + w11*bf2f(r1[5]);
                t2 = w00*bf2f(r0[2]) + w01*bf2f(r0[6]) + w10*bf2f(r1[2]) + w11*bf2f(r1[6]);
            } else {
                int y1 = y0 + 1, x1 = x0 + 1;
                bool vy0 = (y0 >= 0) && (y0 < HH);
                bool vy1 = (y1 >= 0) && (y1 < HH);
                bool vx0 = (x0 >= 0) && (x0 < WWD);
                bool vx1 = (x1 >= 0) && (x1 < WWD);
                float w00 = (vy0 && vx0) ? hy*hx : 0.f;
                float w01 = (vy0 && vx1) ? hy*lx : 0.f;
                float w10 = (vy1 && vx0) ? ly*hx : 0.f;
                float w11 = (vy1 && vx1) ? ly*lx : 0.f;
                int yc0 = min(max(y0, 0), HH-1),  yc1 = min(max(y1, 0), HH-1);
                int xc0 = min(max(x0, 0), WWD-1), xc1 = min(max(x1, 0), WWD-1);
                const float* xb = x + (size_t)b * (3*HH*WWD);
                const float* x0p = xb;
                t0 = w00*x0p[yc0*WWD+xc0] + w01*x0p[yc0*WWD+xc1]
                   + w10*x0p[yc1*WWD+xc0] + w11*x0p[yc1*WWD+xc1];
                const float* x1p = xb + HH*WWD;
                t1 = w00*x1p[yc0*WWD+xc0] + w01*x1p[yc0*WWD+xc1]
                   + w10*x1p[yc1*WWD+xc0] + w11*x1p[yc1*WWD+xc1];
                const float* x2p = xb + 2*HH*WWD;
                t2 = w00*x2p[yc0*WWD+xc0] + w01*x2p[yc0*WWD+xc1]
                   + w10*x2p[yc1*WWD+xc0] + w11*x2p[yc1*WWD+xc1];
            }
            ut[0*9 + k] = f2bf(t0);
            ut[1*9 + k] = f2bf(t1);
            ut[2*9 + k] = f2bf(t2);
        }
        #pragma unroll
        for (int k = 27; k < 32; ++k) ut[k] = 0;

        // --- pack tap half -> chunks 4..7 ---------------------------------
        #pragma unroll
        for (int c8 = 4; c8 < 8; ++c8) {
            const int j0 = (c8 - 4) * 8;
            uint4 v;
            v.x = (unsigned)ut[j0+0] | ((unsigned)ut[j0+1] << 16);
            v.y = (unsigned)ut[j0+2] | ((unsigned)ut[j0+3] << 16);
            v.z = (unsigned)ut[j0+4] | ((unsigned)ut[j0+5] << 16);
            v.w = (unsigned)ut[j0+6] | ((unsigned)ut[j0+7] << 16);
            *(uint4*)(kw + l*128 + ((c8 ^ (l & 7)) << 4)) = v;
        }

        // --- A fragments (both halves) from own LDS region ----------------
        short8 a0[4], a1[4];
        #pragma unroll
        for (int mt = 0; mt < 4; ++mt) {
            int row = mt*16 + r15;
            a0[mt] = *(const short8*)(kw + row*128 + (( g      ^ (row & 7)) << 4));
            a1[mt] = *(const short8*)(kw + row*128 + (((4 + g) ^ (row & 7)) << 4));
        }

        // --- nt-sequential main MFMA + register epilogue ------------------
        #pragma unroll
        for (int nt = 0; nt < 4; ++nt) {
            f32x4 acc[4];
            #pragma unroll
            for (int mt = 0; mt < 4; ++mt)
                acc[mt] = (f32x4){0.f, 0.f, 0.f, 0.f};
            #pragma unroll
            for (int mt = 0; mt < 4; ++mt)
                acc[mt] = __builtin_amdgcn_mfma_f32_16x16x32_bf16(a0[mt], bfr[0][nt], acc[mt], 0, 0, 0);
            #pragma unroll
            for (int mt = 0; mt < 4; ++mt)
                acc[mt] = __builtin_amdgcn_mfma_f32_16x16x32_bf16(a1[mt], bfr[1][nt], acc[mt], 0, 0, 0);

            const float bcv = b_conv[nt*16 + r15];
            float s = 0.f, s2 = 0.f;
            // D layout: ch = nt*16 + r15, px = wv*64 + mt*16 + g*4 + reg
            const size_t base = ((size_t)(b*64 + nt*16 + r15) << 16)
                              + (size_t)h*256 + wv*64 + g*4;
            #pragma unroll
            for (int mt = 0; mt < 4; ++mt) {
                f32x4 v = acc[mt];
                float ox = v.x + bcv, oy = v.y + bcv, oz = v.z + bcv, ow = v.w + bcv;
                s += ox + oy + oz + ow;
                s2 = fmaf(ox, ox, s2); s2 = fmaf(oy, oy, s2);
                s2 = fmaf(oz, oz, s2); s2 = fmaf(ow, ow, s2);
                if (BF16Y) {
                    us4 pv = { f2bf(ox), f2bf(oy), f2bf(oz), f2bf(ow) };
                    *(us4*)(yws + base + mt*16) = pv;
                } else {
                    float4 pv = { ox, oy, oz, ow };
                    *(float4*)(outf + base + mt*16) = pv;
                }
            }
            s  += __shfl_xor(s, 16);  s  += __shfl_xor(s, 32);
            s2 += __shfl_xor(s2, 16); s2 += __shfl_xor(s2, 32);
            if (l < 16) {
                psum[(nt*16 + l)*NBLKW + swz*4 + wv] = s;
                psq [(nt*16 + l)*NBLKW + swz*4 + wv] = s2;
            }
        }

        // --- rotate to next row ------------------------------------------
        if (it == 0) {
            eff = eff_n; swz = swz_n; b = b_n; h = h_n; xpb = xpb_n;
            #pragma unroll
            for (int dy = 0; dy < 3; ++dy) { c8v[dy] = n8[dy]; c4v[dy] = n4[dy]; }
        }
    }
}

// ---------------------------------------------------------------------------
// Kernel 2: reduce per-wave partials -> per-channel scale/shift
// ---------------------------------------------------------------------------
__global__ __launch_bounds__(256) void bn_stats_kernel(
    const float* __restrict__ psum,
    const float* __restrict__ psq,
    const float* __restrict__ gamma,
    const float* __restrict__ beta,
    float* __restrict__ ss)       // [0..63]=scale, [64..127]=shift
{
    __shared__ float rs[256], rq[256];
    const int ch = blockIdx.x, tid = threadIdx.x;
    float s = 0.f, s2 = 0.f;
    for (int j = tid; j < NBLKW; j += 256) {
        s  += psum[ch*NBLKW + j];
        s2 += psq [ch*NBLKW + j];
    }
    rs[tid] = s; rq[tid] = s2;
    __syncthreads();
    for (int st = 128; st > 0; st >>= 1) {
        if (tid < st) { rs[tid] += rs[tid + st]; rq[tid] += rq[tid + st]; }
        __syncthreads();
    }
    if (tid == 0) {
        const float N = (float)NPIX;
        float mean = rs[0] / N;
        float var  = rq[0] / N - mean*mean;
        float rstd = rsqrtf(var + 1e-5f);
        float sc   = gamma[ch] * rstd;
        ss[ch]      = sc;
        ss[64 + ch] = beta[ch] - mean * sc;
    }
}

// ---------------------------------------------------------------------------
// Kernel 3a (bf16 path): read y bf16 from ws (L3-resident), affine + SiLU,
// NON-TEMPORAL fp32 stores to out (write-only -> don't evict y from L3).
// ---------------------------------------------------------------------------
__global__ __launch_bounds__(256) void bn_silu_bf16_kernel(
    const unsigned short* __restrict__ yws,
    float* __restrict__ out,
    const float* __restrict__ ss)
{
    __shared__ float sc[64], sh[64];
    if (threadIdx.x < 64) {
        sc[threadIdx.x] = ss[threadIdx.x];
        sh[threadIdx.x] = ss[64 + threadIdx.x];
    }
    __syncthreads();
    const int total8 = (int)(YTOT / 8);
    for (int i = blockIdx.x*256 + threadIdx.x; i < total8; i += gridDim.x*256) {
        us8 v = *(const us8*)(yws + (size_t)i*8);
        const int o = (i >> 13) & 63;
        const float a = sc[o], t = sh[o];
        float e[8];
        #pragma unroll
        for (int j = 0; j < 8; ++j) {
            float z = fmaf(bf2f(v[j]), a, t);
            e[j] = z / (1.f + __expf(-z));
        }
        f32x4 r0 = { e[0], e[1], e[2], e[3] };
        f32x4 r1 = { e[4], e[5], e[6], e[7] };
        __builtin_nontemporal_store(r0, (f32x4*)(out + (size_t)i*8));
        __builtin_nontemporal_store(r1, (f32x4*)(out + (size_t)i*8 + 4));
    }
}

// ---------------------------------------------------------------------------
// Kernel 3b (fallback): in-place affine + SiLU over fp32 d_out
// ---------------------------------------------------------------------------
__global__ __launch_bounds__(256) void bn_silu_kernel(
    float* __restrict__ y,
    const float* __restrict__ ss)
{
    __shared__ float sc[64], sh[64];
    if (threadIdx.x < 64) {
        sc[threadIdx.x] = ss[threadIdx.x];
        sh[threadIdx.x] = ss[64 + threadIdx.x];
    }
    __syncthreads();
    float4* y4 = (float4*)y;
    const int total4 = (int)(YTOT / 4);
    for (int i = blockIdx.x*256 + threadIdx.x; i < total4; i += gridDim.x*256) {
        float4 v = y4[i];
        const int o = (i >> 14) & 63;
        const float a = sc[o], t = sh[o];
        float z;
        z = fmaf(v.x, a, t); v.x = z / (1.f + __expf(-z));
        z = fmaf(v.y, a, t); v.y = z / (1.f + __expf(-z));
        z = fmaf(v.z, a, t); v.z = z / (1.f + __expf(-z));
        z = fmaf(v.w, a, t); v.w = z / (1.f + __expf(-z));
        y4[i] = v;
    }
}

// ---------------------------------------------------------------------------
extern "C" void kernel_launch(void* const* d_in, const int* in_sizes, int n_in,
                              void* d_out, int out_size, void* d_ws, size_t ws_size,
                              hipStream_t stream) {
    const float* x      = (const float*)d_in[0];
    const float* w_off  = (const float*)d_in[1];
    const float* b_off  = (const float*)d_in[2];
    const float* w_dcn  = (const float*)d_in[3];
    const float* w_conv = (const float*)d_in[4];
    const float* b_conv = (const float*)d_in[5];
    const float* gamma  = (const float*)d_in[6];
    const float* beta   = (const float*)d_in[7];
    float* out = (float*)d_out;

    const size_t yBytes    = YTOT * 2;                        // 128 MiB
    const size_t xpBytes   = (size_t)BB*PW*PW*8;              // 8.65 MB
    const size_t wtgBytes  = 8192 + 2048;                     // wTg + wOg
    const size_t statBytes = 2*(size_t)64*NBLKW*4 + 512;      // ~8.4 MB

    if (ws_size >= yBytes + xpBytes + wtgBytes + statBytes) {
        unsigned short* yws = (unsigned short*)d_ws;
        us4*            xpp = (us4*)((char*)d_ws + yBytes);
        unsigned short* wTg = (unsigned short*)((char*)d_ws + yBytes + xpBytes);
        unsigned short* wOg = wTg + 4096;
        float* psum = (float*)((char*)d_ws + yBytes + xpBytes + wtgBytes);
        float* psq  = psum + (size_t)64*NBLKW;
        float* ss   = psq  + (size_t)64*NBLKW;
        prep_kernel<<<BB*PW, 256, 0, stream>>>(x, xpp);
        wtg_kernel<<<1, 256, 0, stream>>>(w_dcn, w_conv, w_off, wTg, wOg);
        dcn_wave_kernel<true><<<NBLK2, 256, 0, stream>>>(
            x, xpp, wTg, wOg, b_off, b_conv, nullptr, yws, psum, psq);
        bn_stats_kernel<<<64, 256, 0, stream>>>(psum, psq, gamma, beta, ss);
        bn_silu_bf16_kernel<<<2048, 256, 0, stream>>>(yws, out, ss);
    } else {
        // fallback: fp32 y staged in d_out, normalized in place
        us4*            xpp = (us4*)d_ws;
        unsigned short* wTg = (unsigned short*)((char*)d_ws + xpBytes);
        unsigned short* wOg = wTg + 4096;
        float* psum = (float*)((char*)d_ws + xpBytes + wtgBytes);
        float* psq  = psum + (size_t)64*NBLKW;
        float* ss   = psq  + (size_t)64*NBLKW;
        prep_kernel<<<BB*PW, 256, 0, stream>>>(x, xpp);
        wtg_kernel<<<1, 256, 0, stream>>>(w_dcn, w_conv, w_off, wTg, wOg);
        dcn_wave_kernel<false><<<NBLK2, 256, 0, stream>>>(
            x, xpp, wTg, wOg, b_off, b_conv, out, nullptr, psum, psq);
        bn_stats_kernel<<<64, 256, 0, stream>>>(psum, psq, gamma, beta, ss);
        bn_silu_kernel<<<2048, 256, 0, stream>>>(out, ss);
    }
}

// Round 14
// 181.692 us; speedup vs baseline: 1.0559x; 1.0559x over previous
//
#include <hip/hip_runtime.h>
#include <hip/hip_bf16.h>
#include <math.h>

#define BB 16
#define COUTC 64
#define HH 256
#define WWD 256
#define PW 260                // padded width/height (pad=2 each side)
#define NBLK (BB*HH)          // 4096 rows total
#define NBLK2 2048            // K1 grid: each block does 2 rows
#define NBLKW (NBLK*4)        // 16384 per-wave-row stat slots
#define NPIX (BB*HH*WWD)      // 1,048,576 pixels
#define YTOT ((size_t)NPIX*COUTC)   // 67,108,864 y elements

typedef __attribute__((ext_vector_type(8))) short short8;
typedef __attribute__((ext_vector_type(4))) float f32x4;
typedef __attribute__((ext_vector_type(4))) unsigned short us4;
typedef __attribute__((ext_vector_type(8))) unsigned short us8;

__device__ __forceinline__ unsigned short f2bf(float f) {
    __hip_bfloat16 h = __float2bfloat16(f);
    return __builtin_bit_cast(unsigned short, h);
}
__device__ __forceinline__ float bf2f(unsigned short u) {
    unsigned v = (unsigned)u << 16;
    return __builtin_bit_cast(float, v);
}

// ---------------------------------------------------------------------------
// Pre-pass 1: x NCHW fp32 -> zero-padded NHWC bf16  xp[b][y+2][x+2][4].
// ---------------------------------------------------------------------------
__global__ __launch_bounds__(256) void prep_kernel(
    const float* __restrict__ x,
    us4* __restrict__ xp)
{
    const int b  = blockIdx.x / PW;
    const int yr = blockIdx.x % PW - 2;          // y in [-2,257]
    const bool rok = (yr >= 0) && (yr < HH);
    const float* xb = x + (size_t)b * (3*HH*WWD) + (size_t)(rok ? yr : 0)*WWD;
    for (int cx = threadIdx.x; cx < PW; cx += 256) {
        const int xx = cx - 2;
        const bool ok = rok && (xx >= 0) && (xx < WWD);
        float f0 = ok ? xb[0*(HH*WWD) + xx] : 0.f;
        float f1 = ok ? xb[1*(HH*WWD) + xx] : 0.f;
        float f2 = ok ? xb[2*(HH*WWD) + xx] : 0.f;
        us4 v = { f2bf(f0), f2bf(f1), f2bf(f2), 0 };
        xp[((size_t)b*PW + (yr+2))*PW + cx] = v;
    }
}

// ---------------------------------------------------------------------------
// Pre-pass 2: B-fragment tables (pre-swizzled to MFMA layout, L2-hot)
// ---------------------------------------------------------------------------
__global__ __launch_bounds__(256) void wtg_kernel(
    const float* __restrict__ w_dcn,
    const float* __restrict__ w_conv,
    const float* __restrict__ w_off,
    unsigned short* __restrict__ wTg,
    unsigned short* __restrict__ wOg)
{
    for (int e = threadIdx.x; e < 512; e += 256) {
        const int kc = e >> 6, n = e & 63;
        const float* wsrc = (kc < 4) ? w_conv : w_dcn;
        const int kb = (kc & 3) * 8;
        us8 v;
        #pragma unroll
        for (int j = 0; j < 8; ++j) {
            int kk = kb + j;
            v[j] = (kk < 27) ? f2bf(wsrc[n*27 + kk]) : (unsigned short)0;
        }
        *(us8*)(wTg + e*8) = v;
    }
    if (threadIdx.x < 128) {
        const int e = threadIdx.x;
        const int nt2 = e >> 6, l = e & 63;
        const int n = nt2*16 + (l & 15);
        const int kb = (l >> 4) * 8;
        us8 v;
        #pragma unroll
        for (int j = 0; j < 8; ++j) {
            int kk = kb + j;
            v[j] = (n < 18 && kk < 27) ? f2bf(w_off[n*27 + kk]) : (unsigned short)0;
        }
        *(us8*)(wOg + e*8) = v;
    }
}

// ------------------------- per-row helper pieces ---------------------------
__device__ __forceinline__ void load_xn3(const us4* __restrict__ xpb, int h, int w,
                                         us8 r8[3], us4 r4[3])
{
    #pragma unroll
    for (int dy = 0; dy < 3; ++dy) {
        const us4* p = xpb + (unsigned)((h+1+dy)*PW + (w+1));
        r8[dy] = *(const us8*)p;
        r4[dy] = p[2];
    }
}

__device__ __forceinline__ void pack_xn_half(char* kw, int l,
                                             const us8 c8v[3], const us4 c4v[3])
{
    unsigned short u[32];
    #pragma unroll
    for (int c = 0; c < 3; ++c)
        #pragma unroll
        for (int ky = 0; ky < 3; ++ky)
            #pragma unroll
            for (int kx = 0; kx < 3; ++kx)
                u[c*9 + ky*3 + kx] = (kx == 2) ? c4v[ky][c] : c8v[ky][kx*4 + c];
    #pragma unroll
    for (int k = 27; k < 32; ++k) u[k] = 0;
    #pragma unroll
    for (int c8 = 0; c8 < 4; ++c8) {
        uint4 v;
        v.x = (unsigned)u[c8*8+0] | ((unsigned)u[c8*8+1] << 16);
        v.y = (unsigned)u[c8*8+2] | ((unsigned)u[c8*8+3] << 16);
        v.z = (unsigned)u[c8*8+4] | ((unsigned)u[c8*8+5] << 16);
        v.w = (unsigned)u[c8*8+6] | ((unsigned)u[c8*8+7] << 16);
        *(uint4*)(kw + l*128 + ((c8 ^ (l & 7)) << 4)) = v;
    }
}

__device__ __forceinline__ void off_conv_mfma(const char* kw, int g, int r15,
                                              const short8 wof[2], f32x4 dacc[4][2])
{
    short8 af0[4];
    #pragma unroll
    for (int mt = 0; mt < 4; ++mt) {
        int row = mt*16 + r15;
        af0[mt] = *(const short8*)(kw + row*128 + ((g ^ (row & 7)) << 4));
    }
    #pragma unroll
    for (int mt = 0; mt < 4; ++mt)
        #pragma unroll
        for (int nt2 = 0; nt2 < 2; ++nt2) {
            dacc[mt][nt2] = (f32x4){0.f, 0.f, 0.f, 0.f};
            dacc[mt][nt2] = __builtin_amdgcn_mfma_f32_16x16x32_bf16(
                af0[mt], wof[nt2], dacc[mt][nt2], 0, 0, 0);
        }
}

__device__ __forceinline__ void redist_read_off(unsigned short* so, int l, int g,
                                                int r15, const f32x4 dacc[4][2],
                                                const float* __restrict__ b_off,
                                                float off[18])
{
    // D: px = mt*16 + g*4 + reg, ch = nt2*16 + r15
    #pragma unroll
    for (int mt = 0; mt < 4; ++mt)
        #pragma unroll
        for (int nt2 = 0; nt2 < 2; ++nt2) {
            if (nt2 == 1 && r15 >= 2) continue;   // ch 18..31 unused
            #pragma unroll
            for (int r = 0; r < 4; ++r)
                so[(mt*16 + g*4 + r)*24 + nt2*16 + r15] = f2bf(dacc[mt][nt2][r]);
        }
    us8 o0 = *(const us8*)(so + l*24);            // 48B stride: 16B-aligned
    us8 o1 = *(const us8*)(so + l*24 + 8);
    us4 o2 = *(const us4*)(so + l*24 + 16);
    #pragma unroll
    for (int j = 0; j < 8; ++j)  off[j]   = bf2f(o0[j]) + b_off[j];
    #pragma unroll
    for (int j = 0; j < 8; ++j)  off[8+j] = bf2f(o1[j]) + b_off[8+j];
    off[16] = bf2f(o2[0]) + b_off[16];
    off[17] = bf2f(o2[1]) + b_off[17];
}

// Branch-free tap addressing: clamp corner coords to the padded window.
// EXACT for any offset: every OOB corner lands in a zero-pad cell whose
// contribution is 0, matching the reference's validity masking.
__device__ __forceinline__ void tap_addrs(int h, int w, const float off[18],
                                          int o32[9], float W00[9], float W01[9],
                                          float W10[9], float W11[9])
{
    #pragma unroll
    for (int k = 0; k < 9; ++k) {
        const int ky = k / 3, kx = k % 3;
        float py = (float)(h + ky - 1) + off[2*k];
        float px = (float)(w + kx - 1) + off[2*k + 1];
        float y0f = floorf(py), x0f = floorf(px);
        float ly = py - y0f, lx = px - x0f;
        float hy = 1.f - ly, hx = 1.f - lx;
        int y0 = min(max((int)y0f, -2), 256);
        int x0 = min(max((int)x0f, -2), 256);
        o32[k] = (y0 + 2)*PW + (x0 + 2);
        W00[k] = hy*hx; W01[k] = hy*lx; W10[k] = ly*hx; W11[k] = ly*lx;
    }
}

__device__ __forceinline__ void tap_loads(const us4* __restrict__ xpb,
                                          const int o32[9], us8 ra[9], us8 rb[9])
{
    #pragma unroll
    for (int k = 0; k < 9; ++k) {
        const us4* p0 = xpb + (unsigned)o32[k];
        ra[k] = *(const us8*)p0;          // (y0,x0),(y0,x0+1) x 3ch
        rb[k] = *(const us8*)(p0 + PW);   // (y0+1,x0),(y0+1,x0+1) x 3ch
    }
}

__device__ __forceinline__ void tap_math_pack(char* kw, int l,
                                              const float W00[9], const float W01[9],
                                              const float W10[9], const float W11[9],
                                              const us8 ra[9], const us8 rb[9])
{
    unsigned short ut[32];
    #pragma unroll
    for (int k = 0; k < 9; ++k) {
        #pragma unroll
        for (int c = 0; c < 3; ++c) {
            float t = W00[k]*bf2f(ra[k][c])   + W01[k]*bf2f(ra[k][4+c])
                    + W10[k]*bf2f(rb[k][c])   + W11[k]*bf2f(rb[k][4+c]);
            ut[c*9 + k] = f2bf(t);
        }
    }
    #pragma unroll
    for (int k = 27; k < 32; ++k) ut[k] = 0;
    #pragma unroll
    for (int c8 = 4; c8 < 8; ++c8) {
        const int j0 = (c8 - 4) * 8;
        uint4 v;
        v.x = (unsigned)ut[j0+0] | ((unsigned)ut[j0+1] << 16);
        v.y = (unsigned)ut[j0+2] | ((unsigned)ut[j0+3] << 16);
        v.z = (unsigned)ut[j0+4] | ((unsigned)ut[j0+5] << 16);
        v.w = (unsigned)ut[j0+6] | ((unsigned)ut[j0+7] << 16);
        *(uint4*)(kw + l*128 + ((c8 ^ (l & 7)) << 4)) = v;
    }
}

template<bool BF16Y>
__device__ __forceinline__ void main_mfma_epilogue(
    const char* kw, int l, int wv, int g, int r15,
    const short8 bfr[2][4], const float* __restrict__ b_conv,
    int swz, int b, int h,
    float* __restrict__ outf, unsigned short* __restrict__ yws,
    float* __restrict__ psum, float* __restrict__ psq)
{
    short8 a0[4], a1[4];
    #pragma unroll
    for (int mt = 0; mt < 4; ++mt) {
        int row = mt*16 + r15;
        a0[mt] = *(const short8*)(kw + row*128 + (( g      ^ (row & 7)) << 4));
        a1[mt] = *(const short8*)(kw + row*128 + (((4 + g) ^ (row & 7)) << 4));
    }
    #pragma unroll
    for (int nt = 0; nt < 4; ++nt) {
        f32x4 acc[4];
        #pragma unroll
        for (int mt = 0; mt < 4; ++mt)
            acc[mt] = (f32x4){0.f, 0.f, 0.f, 0.f};
        #pragma unroll
        for (int mt = 0; mt < 4; ++mt)
            acc[mt] = __builtin_amdgcn_mfma_f32_16x16x32_bf16(a0[mt], bfr[0][nt], acc[mt], 0, 0, 0);
        #pragma unroll
        for (int mt = 0; mt < 4; ++mt)
            acc[mt] = __builtin_amdgcn_mfma_f32_16x16x32_bf16(a1[mt], bfr[1][nt], acc[mt], 0, 0, 0);

        const float bcv = b_conv[nt*16 + r15];
        float s = 0.f, s2 = 0.f;
        // D layout: ch = nt*16 + r15, px = wv*64 + mt*16 + g*4 + reg
        const size_t base = ((size_t)(b*64 + nt*16 + r15) << 16)
                          + (size_t)h*256 + wv*64 + g*4;
        #pragma unroll
        for (int mt = 0; mt < 4; ++mt) {
            f32x4 v = acc[mt];
            float ox = v.x + bcv, oy = v.y + bcv, oz = v.z + bcv, ow = v.w + bcv;
            s += ox + oy + oz + ow;
            s2 = fmaf(ox, ox, s2); s2 = fmaf(oy, oy, s2);
            s2 = fmaf(oz, oz, s2); s2 = fmaf(ow, ow, s2);
            if (BF16Y) {
                us4 pv = { f2bf(ox), f2bf(oy), f2bf(oz), f2bf(ow) };
                *(us4*)(yws + base + mt*16) = pv;
            } else {
                float4 pv = { ox, oy, oz, ow };
                *(float4*)(outf + base + mt*16) = pv;
            }
        }
        s  += __shfl_xor(s, 16);  s  += __shfl_xor(s, 32);
        s2 += __shfl_xor(s2, 16); s2 += __shfl_xor(s2, 32);
        if (l < 16) {
            psum[(nt*16 + l)*NBLKW + swz*4 + wv] = s;
            psq [(nt*16 + l)*NBLKW + swz*4 + wv] = s2;
        }
    }
}

// ---------------------------------------------------------------------------
// Kernel 1: wave-autonomous, zero barriers, 2 rows/block with TRUE chain
// interleave: row0 tap-load latency hides under row1 addr math; row1
// tap-load latency hides under row0's 32-MFMA + epilogue. Branch-free taps.
// Per-row private LDS A-tile halves (76 KB total -> 2 blocks/CU).
// ---------------------------------------------------------------------------
template<bool BF16Y>
__global__ __launch_bounds__(256, 2) void dcn_wave_kernel(
    const us4* __restrict__ xp,
    const unsigned short* __restrict__ wTg,
    const unsigned short* __restrict__ wOg,
    const float* __restrict__ b_off,
    const float* __restrict__ b_conv,
    float* __restrict__ outf,
    unsigned short* __restrict__ yws,
    float* __restrict__ psum,     // [64][NBLKW]
    float* __restrict__ psq)      // [64][NBLKW]
{
    __shared__ __align__(16) char kbuf[65536];              // 2 rows x 4 waves x 8KB
    __shared__ __align__(16) unsigned short sofs[6144];     // 4 waves x 64 x 24

    const int tid = threadIdx.x;
    const int bid = blockIdx.x;
    const int w = tid;
    const int l   = tid & 63;
    const int wv  = tid >> 6;
    const int g   = l >> 4;
    const int r15 = l & 15;
    char* kw0 = kbuf + wv*8192;
    char* kw1 = kbuf + (4 + wv)*8192;
    unsigned short* so = sofs + wv*64*24;

    // row ids (XCD-bijective over 4096)
    const int eff0 = bid,         eff1 = bid + NBLK2;
    const int swz0 = ((eff0 & 7) << 9) | (eff0 >> 3);
    const int swz1 = ((eff1 & 7) << 9) | ((eff1 >> 3) & 511);
    const int b0 = swz0 >> 8, h0 = swz0 & 255;
    const int b1 = swz1 >> 8, h1 = swz1 & 255;
    const us4* xpb0 = xp + (size_t)b0*PW*PW;
    const us4* xpb1 = xp + (size_t)b1*PW*PW;

    // weight fragments (once per block, L2-hot)
    short8 bfr[2][4];
    #pragma unroll
    for (int ks = 0; ks < 2; ++ks)
        #pragma unroll
        for (int nt = 0; nt < 4; ++nt) {
            const int kc = ks*4 + g, n = nt*16 + r15;
            bfr[ks][nt] = *(const short8*)(wTg + (kc*64 + n)*8);
        }
    short8 wof[2];
    #pragma unroll
    for (int nt2 = 0; nt2 < 2; ++nt2)
        wof[nt2] = *(const short8*)(wOg + (nt2*64 + l)*8);

    // xn for both rows (12 independent wide loads, issued together)
    us8 c8v0[3]; us4 c4v0[3];
    us8 c8v1[3]; us4 c4v1[3];
    load_xn3(xpb0, h0, w, c8v0, c4v0);
    load_xn3(xpb1, h1, w, c8v1, c4v1);

    // pack xn halves into per-row LDS tiles
    pack_xn_half(kw0, l, c8v0, c4v0);
    pack_xn_half(kw1, l, c8v1, c4v1);

    // offset conv on MFMA, both rows
    f32x4 dacc0[4][2], dacc1[4][2];
    off_conv_mfma(kw0, g, r15, wof, dacc0);
    off_conv_mfma(kw1, g, r15, wof, dacc1);

    // redistribute -> per-pixel offsets (so reused sequentially, wave-private)
    float off0[18], off1[18];
    redist_read_off(so, l, g, r15, dacc0, b_off, off0);
    redist_read_off(so, l, g, r15, dacc1, b_off, off1);

    // --- row0 gather issued; row1 addr math covers its latency ------------
    int o32_0[9]; float W00_0[9], W01_0[9], W10_0[9], W11_0[9];
    tap_addrs(h0, w, off0, o32_0, W00_0, W01_0, W10_0, W11_0);
    us8 ra0[9], rb0[9];
    tap_loads(xpb0, o32_0, ra0, rb0);

    int o32_1[9]; float W00_1[9], W01_1[9], W10_1[9], W11_1[9];
    tap_addrs(h1, w, off1, o32_1, W00_1, W01_1, W10_1, W11_1);

    // row0 math + pack
    tap_math_pack(kw0, l, W00_0, W01_0, W10_0, W11_0, ra0, rb0);

    // --- row1 gather issued; row0 main MFMA + epilogue covers it ----------
    us8 ra1[9], rb1[9];
    tap_loads(xpb1, o32_1, ra1, rb1);

    main_mfma_epilogue<BF16Y>(kw0, l, wv, g, r15, bfr, b_conv,
                              swz0, b0, h0, outf, yws, psum, psq);

    // row1 math + pack + main
    tap_math_pack(kw1, l, W00_1, W01_1, W10_1, W11_1, ra1, rb1);
    main_mfma_epilogue<BF16Y>(kw1, l, wv, g, r15, bfr, b_conv,
                              swz1, b1, h1, outf, yws, psum, psq);
}

// ---------------------------------------------------------------------------
// Kernel 2: reduce per-wave partials -> per-channel scale/shift
// ---------------------------------------------------------------------------
__global__ __launch_bounds__(256) void bn_stats_kernel(
    const float* __restrict__ psum,
    const float* __restrict__ psq,
    const float* __restrict__ gamma,
    const float* __restrict__ beta,
    float* __restrict__ ss)       // [0..63]=scale, [64..127]=shift
{
    __shared__ float rs[256], rq[256];
    const int ch = blockIdx.x, tid = threadIdx.x;
    float s = 0.f, s2 = 0.f;
    for (int j = tid; j < NBLKW; j += 256) {
        s  += psum[ch*NBLKW + j];
        s2 += psq [ch*NBLKW + j];
    }
    rs[tid] = s; rq[tid] = s2;
    __syncthreads();
    for (int st = 128; st > 0; st >>= 1) {
        if (tid < st) { rs[tid] += rs[tid + st]; rq[tid] += rq[tid + st]; }
        __syncthreads();
    }
    if (tid == 0) {
        const float N = (float)NPIX;
        float mean = rs[0] / N;
        float var  = rq[0] / N - mean*mean;
        float rstd = rsqrtf(var + 1e-5f);
        float sc   = gamma[ch] * rstd;
        ss[ch]      = sc;
        ss[64 + ch] = beta[ch] - mean * sc;
    }
}

// ---------------------------------------------------------------------------
// Kernel 3a (bf16 path): read y bf16 from ws, affine + SiLU, fp32 out
// (plain stores — nt-store regressed in R13)
// ---------------------------------------------------------------------------
__global__ __launch_bounds__(256) void bn_silu_bf16_kernel(
    const unsigned short* __restrict__ yws,
    float* __restrict__ out,
    const float* __restrict__ ss)
{
    __shared__ float sc[64], sh[64];
    if (threadIdx.x < 64) {
        sc[threadIdx.x] = ss[threadIdx.x];
        sh[threadIdx.x] = ss[64 + threadIdx.x];
    }
    __syncthreads();
    const int total8 = (int)(YTOT / 8);
    for (int i = blockIdx.x*256 + threadIdx.x; i < total8; i += gridDim.x*256) {
        us8 v = *(const us8*)(yws + (size_t)i*8);
        const int o = (i >> 13) & 63;
        const float a = sc[o], t = sh[o];
        float e[8];
        #pragma unroll
        for (int j = 0; j < 8; ++j) {
            float z = fmaf(bf2f(v[j]), a, t);
            e[j] = z / (1.f + __expf(-z));
        }
        float4 r0 = { e[0], e[1], e[2], e[3] };
        float4 r1 = { e[4], e[5], e[6], e[7] };
        *(float4*)(out + (size_t)i*8)     = r0;
        *(float4*)(out + (size_t)i*8 + 4) = r1;
    }
}

// ---------------------------------------------------------------------------
// Kernel 3b (fallback): in-place affine + SiLU over fp32 d_out
// ---------------------------------------------------------------------------
__global__ __launch_bounds__(256) void bn_silu_kernel(
    float* __restrict__ y,
    const float* __restrict__ ss)
{
    __shared__ float sc[64], sh[64];
    if (threadIdx.x < 64) {
        sc[threadIdx.x] = ss[threadIdx.x];
        sh[threadIdx.x] = ss[64 + threadIdx.x];
    }
    __syncthreads();
    float4* y4 = (float4*)y;
    const int total4 = (int)(YTOT / 4);
    for (int i = blockIdx.x*256 + threadIdx.x; i < total4; i += gridDim.x*256) {
        float4 v = y4[i];
        const int o = (i >> 14) & 63;
        const float a = sc[o], t = sh[o];
        float z;
        z = fmaf(v.x, a, t); v.x = z / (1.f + __expf(-z));
        z = fmaf(v.y, a, t); v.y = z / (1.f + __expf(-z));
        z = fmaf(v.z, a, t); v.z = z / (1.f + __expf(-z));
        z = fmaf(v.w, a, t); v.w = z / (1.f + __expf(-z));
        y4[i] = v;
    }
}

// ---------------------------------------------------------------------------
extern "C" void kernel_launch(void* const* d_in, const int* in_sizes, int n_in,
                              void* d_out, int out_size, void* d_ws, size_t ws_size,
                              hipStream_t stream) {
    const float* x      = (const float*)d_in[0];
    const float* w_off  = (const float*)d_in[1];
    const float* b_off  = (const float*)d_in[2];
    const float* w_dcn  = (const float*)d_in[3];
    const float* w_conv = (const float*)d_in[4];
    const float* b_conv = (const float*)d_in[5];
    const float* gamma  = (const float*)d_in[6];
    const float* beta   = (const float*)d_in[7];
    float* out = (float*)d_out;

    const size_t yBytes    = YTOT * 2;                        // 128 MiB
    const size_t xpBytes   = (size_t)BB*PW*PW*8;              // 8.65 MB
    const size_t wtgBytes  = 8192 + 2048;                     // wTg + wOg
    const size_t statBytes = 2*(size_t)64*NBLKW*4 + 512;      // ~8.4 MB

    if (ws_size >= yBytes + xpBytes + wtgBytes + statBytes) {
        unsigned short* yws = (unsigned short*)d_ws;
        us4*            xpp = (us4*)((char*)d_ws + yBytes);
        unsigned short* wTg = (unsigned short*)((char*)d_ws + yBytes + xpBytes);
        unsigned short* wOg = wTg + 4096;
        float* psum = (float*)((char*)d_ws + yBytes + xpBytes + wtgBytes);
        float* psq  = psum + (size_t)64*NBLKW;
        float* ss   = psq  + (size_t)64*NBLKW;
        prep_kernel<<<BB*PW, 256, 0, stream>>>(x, xpp);
        wtg_kernel<<<1, 256, 0, stream>>>(w_dcn, w_conv, w_off, wTg, wOg);
        dcn_wave_kernel<true><<<NBLK2, 256, 0, stream>>>(
            xpp, wTg, wOg, b_off, b_conv, nullptr, yws, psum, psq);
        bn_stats_kernel<<<64, 256, 0, stream>>>(psum, psq, gamma, beta, ss);
        bn_silu_bf16_kernel<<<2048, 256, 0, stream>>>(yws, out, ss);
    } else {
        // fallback: fp32 y staged in d_out, normalized in place
        us4*            xpp = (us4*)d_ws;
        unsigned short* wTg = (unsigned short*)((char*)d_ws + xpBytes);
        unsigned short* wOg = wTg + 4096;
        float* psum = (float*)((char*)d_ws + xpBytes + wtgBytes);
        float* psq  = psum + (size_t)64*NBLKW;
        float* ss   = psq  + (size_t)64*NBLKW;
        prep_kernel<<<BB*PW, 256, 0, stream>>>(x, xpp);
        wtg_kernel<<<1, 256, 0, stream>>>(w_dcn, w_conv, w_off, wTg, wOg);
        dcn_wave_kernel<false><<<NBLK2, 256, 0, stream>>>(
            xpp, wTg, wOg, b_off, b_conv, out, nullptr, psum, psq);
        bn_stats_kernel<<<64, 256, 0, stream>>>(psum, psq, gamma, beta, ss);
        bn_silu_kernel<<<2048, 256, 0, stream>>>(out, ss);
    }
}

// Round 15
// 173.412 us; speedup vs baseline: 1.1063x; 1.0478x over previous
//
#include <hip/hip_runtime.h>
#include <hip/hip_bf16.h>
#include <math.h>

#define BB 16
#define COUTC 64
#define HH 256
#define WWD 256
#define PW 260                // padded width/height (pad=2 each side)
#define NBLK (BB*HH)          // 4096 rows total
#define NBLK2 2048            // K1 grid: each block does 2 rows
#define NBLKW (NBLK*4)        // 16384 per-wave-row stat slots
#define NPIX (BB*HH*WWD)      // 1,048,576 pixels
#define YTOT ((size_t)NPIX*COUTC)   // 67,108,864 y elements

typedef __attribute__((ext_vector_type(8))) short short8;
typedef __attribute__((ext_vector_type(4))) float f32x4;
typedef __attribute__((ext_vector_type(4))) unsigned short us4;
typedef __attribute__((ext_vector_type(8))) unsigned short us8;

__device__ __forceinline__ unsigned short f2bf(float f) {
    __hip_bfloat16 h = __float2bfloat16(f);
    return __builtin_bit_cast(unsigned short, h);
}
__device__ __forceinline__ float bf2f(unsigned short u) {
    unsigned v = (unsigned)u << 16;
    return __builtin_bit_cast(float, v);
}

// ---------------------------------------------------------------------------
// Pre-pass 1: x NCHW fp32 -> zero-padded NHWC bf16  xp[b][y+2][x+2][4].
// ---------------------------------------------------------------------------
__global__ __launch_bounds__(256) void prep_kernel(
    const float* __restrict__ x,
    us4* __restrict__ xp)
{
    const int b  = blockIdx.x / PW;
    const int yr = blockIdx.x % PW - 2;          // y in [-2,257]
    const bool rok = (yr >= 0) && (yr < HH);
    const float* xb = x + (size_t)b * (3*HH*WWD) + (size_t)(rok ? yr : 0)*WWD;
    for (int cx = threadIdx.x; cx < PW; cx += 256) {
        const int xx = cx - 2;
        const bool ok = rok && (xx >= 0) && (xx < WWD);
        float f0 = ok ? xb[0*(HH*WWD) + xx] : 0.f;
        float f1 = ok ? xb[1*(HH*WWD) + xx] : 0.f;
        float f2 = ok ? xb[2*(HH*WWD) + xx] : 0.f;
        us4 v = { f2bf(f0), f2bf(f1), f2bf(f2), 0 };
        xp[((size_t)b*PW + (yr+2))*PW + cx] = v;
    }
}

// ---------------------------------------------------------------------------
// Pre-pass 2: B-fragment tables (pre-swizzled to MFMA layout, L2-hot)
// ---------------------------------------------------------------------------
__global__ __launch_bounds__(256) void wtg_kernel(
    const float* __restrict__ w_dcn,
    const float* __restrict__ w_conv,
    const float* __restrict__ w_off,
    unsigned short* __restrict__ wTg,
    unsigned short* __restrict__ wOg)
{
    for (int e = threadIdx.x; e < 512; e += 256) {
        const int kc = e >> 6, n = e & 63;
        const float* wsrc = (kc < 4) ? w_conv : w_dcn;
        const int kb = (kc & 3) * 8;
        us8 v;
        #pragma unroll
        for (int j = 0; j < 8; ++j) {
            int kk = kb + j;
            v[j] = (kk < 27) ? f2bf(wsrc[n*27 + kk]) : (unsigned short)0;
        }
        *(us8*)(wTg + e*8) = v;
    }
    if (threadIdx.x < 128) {
        const int e = threadIdx.x;
        const int nt2 = e >> 6, l = e & 63;
        const int n = nt2*16 + (l & 15);
        const int kb = (l >> 4) * 8;
        us8 v;
        #pragma unroll
        for (int j = 0; j < 8; ++j) {
            int kk = kb + j;
            v[j] = (n < 18 && kk < 27) ? f2bf(w_off[n*27 + kk]) : (unsigned short)0;
        }
        *(us8*)(wOg + e*8) = v;
    }
}

// ------------------------- per-row helper pieces ---------------------------
__device__ __forceinline__ void load_xn3(const us4* __restrict__ xpb, int h, int w,
                                         us8 r8[3], us4 r4[3])
{
    #pragma unroll
    for (int dy = 0; dy < 3; ++dy) {
        const us4* p = xpb + (unsigned)((h+1+dy)*PW + (w+1));
        r8[dy] = *(const us8*)p;
        r4[dy] = p[2];
    }
}

__device__ __forceinline__ void pack_xn_half(char* kw, int l,
                                             const us8 c8v[3], const us4 c4v[3])
{
    unsigned short u[32];
    #pragma unroll
    for (int c = 0; c < 3; ++c)
        #pragma unroll
        for (int ky = 0; ky < 3; ++ky)
            #pragma unroll
            for (int kx = 0; kx < 3; ++kx)
                u[c*9 + ky*3 + kx] = (kx == 2) ? c4v[ky][c] : c8v[ky][kx*4 + c];
    #pragma unroll
    for (int k = 27; k < 32; ++k) u[k] = 0;
    #pragma unroll
    for (int c8 = 0; c8 < 4; ++c8) {
        uint4 v;
        v.x = (unsigned)u[c8*8+0] | ((unsigned)u[c8*8+1] << 16);
        v.y = (unsigned)u[c8*8+2] | ((unsigned)u[c8*8+3] << 16);
        v.z = (unsigned)u[c8*8+4] | ((unsigned)u[c8*8+5] << 16);
        v.w = (unsigned)u[c8*8+6] | ((unsigned)u[c8*8+7] << 16);
        *(uint4*)(kw + l*128 + ((c8 ^ (l & 7)) << 4)) = v;
    }
}

__device__ __forceinline__ void off_conv_mfma(const char* kw, int g, int r15,
                                              const short8 wof[2], f32x4 dacc[4][2])
{
    short8 af0[4];
    #pragma unroll
    for (int mt = 0; mt < 4; ++mt) {
        int row = mt*16 + r15;
        af0[mt] = *(const short8*)(kw + row*128 + ((g ^ (row & 7)) << 4));
    }
    #pragma unroll
    for (int mt = 0; mt < 4; ++mt)
        #pragma unroll
        for (int nt2 = 0; nt2 < 2; ++nt2) {
            dacc[mt][nt2] = (f32x4){0.f, 0.f, 0.f, 0.f};
            dacc[mt][nt2] = __builtin_amdgcn_mfma_f32_16x16x32_bf16(
                af0[mt], wof[nt2], dacc[mt][nt2], 0, 0, 0);
        }
}

__device__ __forceinline__ void redist_read_off(unsigned short* so, int l, int g,
                                                int r15, const f32x4 dacc[4][2],
                                                const float* __restrict__ b_off,
                                                float off[18])
{
    // D: px = mt*16 + g*4 + reg, ch = nt2*16 + r15
    #pragma unroll
    for (int mt = 0; mt < 4; ++mt)
        #pragma unroll
        for (int nt2 = 0; nt2 < 2; ++nt2) {
            if (nt2 == 1 && r15 >= 2) continue;   // ch 18..31 unused
            #pragma unroll
            for (int r = 0; r < 4; ++r)
                so[(mt*16 + g*4 + r)*24 + nt2*16 + r15] = f2bf(dacc[mt][nt2][r]);
        }
    us8 o0 = *(const us8*)(so + l*24);            // 48B stride: 16B-aligned
    us8 o1 = *(const us8*)(so + l*24 + 8);
    us4 o2 = *(const us4*)(so + l*24 + 16);
    #pragma unroll
    for (int j = 0; j < 8; ++j)  off[j]   = bf2f(o0[j]) + b_off[j];
    #pragma unroll
    for (int j = 0; j < 8; ++j)  off[8+j] = bf2f(o1[j]) + b_off[8+j];
    off[16] = bf2f(o2[0]) + b_off[16];
    off[17] = bf2f(o2[1]) + b_off[17];
}

// Branch-free tap addressing: clamp corner coords to the padded window.
// EXACT for any offset: every OOB corner lands in a zero-pad cell whose
// contribution is 0, matching the reference's validity masking.
__device__ __forceinline__ void tap_addrs(int h, int w, const float off[18],
                                          int o32[9], float W00[9], float W01[9],
                                          float W10[9], float W11[9])
{
    #pragma unroll
    for (int k = 0; k < 9; ++k) {
        const int ky = k / 3, kx = k % 3;
        float py = (float)(h + ky - 1) + off[2*k];
        float px = (float)(w + kx - 1) + off[2*k + 1];
        float y0f = floorf(py), x0f = floorf(px);
        float ly = py - y0f, lx = px - x0f;
        float hy = 1.f - ly, hx = 1.f - lx;
        int y0 = min(max((int)y0f, -2), 256);
        int x0 = min(max((int)x0f, -2), 256);
        o32[k] = (y0 + 2)*PW + (x0 + 2);
        W00[k] = hy*hx; W01[k] = hy*lx; W10[k] = ly*hx; W11[k] = ly*lx;
    }
}

__device__ __forceinline__ void tap_loads(const us4* __restrict__ xpb,
                                          const int o32[9], us8 ra[9], us8 rb[9])
{
    #pragma unroll
    for (int k = 0; k < 9; ++k) {
        const us4* p0 = xpb + (unsigned)o32[k];
        ra[k] = *(const us8*)p0;          // (y0,x0),(y0,x0+1) x 3ch
        rb[k] = *(const us8*)(p0 + PW);   // (y0+1,x0),(y0+1,x0+1) x 3ch
    }
}

__device__ __forceinline__ void tap_math_pack(char* kw, int l,
                                              const float W00[9], const float W01[9],
                                              const float W10[9], const float W11[9],
                                              const us8 ra[9], const us8 rb[9])
{
    unsigned short ut[32];
    #pragma unroll
    for (int k = 0; k < 9; ++k) {
        #pragma unroll
        for (int c = 0; c < 3; ++c) {
            float t = W00[k]*bf2f(ra[k][c])   + W01[k]*bf2f(ra[k][4+c])
                    + W10[k]*bf2f(rb[k][c])   + W11[k]*bf2f(rb[k][4+c]);
            ut[c*9 + k] = f2bf(t);
        }
    }
    #pragma unroll
    for (int k = 27; k < 32; ++k) ut[k] = 0;
    #pragma unroll
    for (int c8 = 4; c8 < 8; ++c8) {
        const int j0 = (c8 - 4) * 8;
        uint4 v;
        v.x = (unsigned)ut[j0+0] | ((unsigned)ut[j0+1] << 16);
        v.y = (unsigned)ut[j0+2] | ((unsigned)ut[j0+3] << 16);
        v.z = (unsigned)ut[j0+4] | ((unsigned)ut[j0+5] << 16);
        v.w = (unsigned)ut[j0+6] | ((unsigned)ut[j0+7] << 16);
        *(uint4*)(kw + l*128 + ((c8 ^ (l & 7)) << 4)) = v;
    }
}

// Epilogue with per-wave LDS store-transpose (BF16Y path): D-fragment ->
// tr[16ch][64px] bf16 (stride 136B) -> 4-channel us4 stores = 128B
// contiguous per channel (8 full lines/instr vs 16 partial lines direct).
template<bool BF16Y>
__device__ __forceinline__ void main_mfma_epilogue(
    const char* kw, unsigned short* trw, int l, int wv, int g, int r15,
    const short8 bfr[2][4], const float* __restrict__ b_conv,
    int swz, int b, int h,
    float* __restrict__ outf, unsigned short* __restrict__ yws,
    float* __restrict__ psum, float* __restrict__ psq)
{
    char* tr = (char*)trw;          // per-wave 3072B scratch; 16*136=2176 used
    short8 a0[4], a1[4];
    #pragma unroll
    for (int mt = 0; mt < 4; ++mt) {
        int row = mt*16 + r15;
        a0[mt] = *(const short8*)(kw + row*128 + (( g      ^ (row & 7)) << 4));
        a1[mt] = *(const short8*)(kw + row*128 + (((4 + g) ^ (row & 7)) << 4));
    }
    #pragma unroll
    for (int nt = 0; nt < 4; ++nt) {
        f32x4 acc[4];
        #pragma unroll
        for (int mt = 0; mt < 4; ++mt)
            acc[mt] = (f32x4){0.f, 0.f, 0.f, 0.f};
        #pragma unroll
        for (int mt = 0; mt < 4; ++mt)
            acc[mt] = __builtin_amdgcn_mfma_f32_16x16x32_bf16(a0[mt], bfr[0][nt], acc[mt], 0, 0, 0);
        #pragma unroll
        for (int mt = 0; mt < 4; ++mt)
            acc[mt] = __builtin_amdgcn_mfma_f32_16x16x32_bf16(a1[mt], bfr[1][nt], acc[mt], 0, 0, 0);

        const float bcv = b_conv[nt*16 + r15];
        float s = 0.f, s2 = 0.f;
        // D layout: ch = nt*16 + r15, px(wave-local) = mt*16 + g*4 + reg
        #pragma unroll
        for (int mt = 0; mt < 4; ++mt) {
            f32x4 v = acc[mt];
            float ox = v.x + bcv, oy = v.y + bcv, oz = v.z + bcv, ow = v.w + bcv;
            s += ox + oy + oz + ow;
            s2 = fmaf(ox, ox, s2); s2 = fmaf(oy, oy, s2);
            s2 = fmaf(oz, oz, s2); s2 = fmaf(ow, ow, s2);
            if (BF16Y) {
                us4 pv = { f2bf(ox), f2bf(oy), f2bf(oz), f2bf(ow) };
                // tr[ch-local r15][px mt*16+g*4], stride 136B (8-aligned)
                *(us4*)(tr + r15*136 + (mt*16 + g*4)*2) = pv;
            } else {
                const size_t base = ((size_t)(b*64 + nt*16 + r15) << 16)
                                  + (size_t)h*256 + wv*64 + g*4;
                float4 pv = { ox, oy, oz, ow };
                *(float4*)(outf + base + mt*16) = pv;
            }
        }
        if (BF16Y) {
            // 4 channels per store instr: lane -> ch-local j*4+g, px r15*4..+3
            #pragma unroll
            for (int j = 0; j < 4; ++j) {
                us4 q = *(const us4*)(tr + (j*4 + g)*136 + r15*8);
                const size_t base = ((size_t)(b*64 + nt*16 + j*4 + g) << 16)
                                  + (size_t)h*256 + wv*64 + r15*4;
                *(us4*)(yws + base) = q;
            }
        }
        s  += __shfl_xor(s, 16);  s  += __shfl_xor(s, 32);
        s2 += __shfl_xor(s2, 16); s2 += __shfl_xor(s2, 32);
        if (l < 16) {
            psum[(nt*16 + l)*NBLKW + swz*4 + wv] = s;
            psq [(nt*16 + l)*NBLKW + swz*4 + wv] = s2;
        }
    }
}

// ---------------------------------------------------------------------------
// Kernel 1: wave-autonomous, zero barriers, 2 rows/block chain-interleaved
// (R14 structure) + LDS store-transpose epilogue. Branch-free taps.
// ---------------------------------------------------------------------------
template<bool BF16Y>
__global__ __launch_bounds__(256, 2) void dcn_wave_kernel(
    const us4* __restrict__ xp,
    const unsigned short* __restrict__ wTg,
    const unsigned short* __restrict__ wOg,
    const float* __restrict__ b_off,
    const float* __restrict__ b_conv,
    float* __restrict__ outf,
    unsigned short* __restrict__ yws,
    float* __restrict__ psum,     // [64][NBLKW]
    float* __restrict__ psq)      // [64][NBLKW]
{
    __shared__ __align__(16) char kbuf[65536];              // 2 rows x 4 waves x 8KB
    __shared__ __align__(16) unsigned short sofs[6144];     // 4 waves x 3072B

    const int tid = threadIdx.x;
    const int bid = blockIdx.x;
    const int w = tid;
    const int l   = tid & 63;
    const int wv  = tid >> 6;
    const int g   = l >> 4;
    const int r15 = l & 15;
    char* kw0 = kbuf + wv*8192;
    char* kw1 = kbuf + (4 + wv)*8192;
    unsigned short* so = sofs + wv*1536;    // 3072B per wave

    // row ids (XCD-bijective over 4096)
    const int eff0 = bid,         eff1 = bid + NBLK2;
    const int swz0 = ((eff0 & 7) << 9) | (eff0 >> 3);
    const int swz1 = ((eff1 & 7) << 9) | ((eff1 >> 3) & 511);
    const int b0 = swz0 >> 8, h0 = swz0 & 255;
    const int b1 = swz1 >> 8, h1 = swz1 & 255;
    const us4* xpb0 = xp + (size_t)b0*PW*PW;
    const us4* xpb1 = xp + (size_t)b1*PW*PW;

    // weight fragments (once per block, L2-hot)
    short8 bfr[2][4];
    #pragma unroll
    for (int ks = 0; ks < 2; ++ks)
        #pragma unroll
        for (int nt = 0; nt < 4; ++nt) {
            const int kc = ks*4 + g, n = nt*16 + r15;
            bfr[ks][nt] = *(const short8*)(wTg + (kc*64 + n)*8);
        }
    short8 wof[2];
    #pragma unroll
    for (int nt2 = 0; nt2 < 2; ++nt2)
        wof[nt2] = *(const short8*)(wOg + (nt2*64 + l)*8);

    // xn for both rows (12 independent wide loads, issued together)
    us8 c8v0[3]; us4 c4v0[3];
    us8 c8v1[3]; us4 c4v1[3];
    load_xn3(xpb0, h0, w, c8v0, c4v0);
    load_xn3(xpb1, h1, w, c8v1, c4v1);

    // pack xn halves into per-row LDS tiles
    pack_xn_half(kw0, l, c8v0, c4v0);
    pack_xn_half(kw1, l, c8v1, c4v1);

    // offset conv on MFMA, both rows
    f32x4 dacc0[4][2], dacc1[4][2];
    off_conv_mfma(kw0, g, r15, wof, dacc0);
    off_conv_mfma(kw1, g, r15, wof, dacc1);

    // redistribute -> per-pixel offsets (so reused sequentially, wave-private)
    float off0[18], off1[18];
    redist_read_off(so, l, g, r15, dacc0, b_off, off0);
    redist_read_off(so, l, g, r15, dacc1, b_off, off1);

    // --- row0 gather issued; row1 addr math covers its latency ------------
    int o32_0[9]; float W00_0[9], W01_0[9], W10_0[9], W11_0[9];
    tap_addrs(h0, w, off0, o32_0, W00_0, W01_0, W10_0, W11_0);
    us8 ra0[9], rb0[9];
    tap_loads(xpb0, o32_0, ra0, rb0);

    int o32_1[9]; float W00_1[9], W01_1[9], W10_1[9], W11_1[9];
    tap_addrs(h1, w, off1, o32_1, W00_1, W01_1, W10_1, W11_1);

    // row0 math + pack
    tap_math_pack(kw0, l, W00_0, W01_0, W10_0, W11_0, ra0, rb0);

    // --- row1 gather issued; row0 main MFMA + epilogue covers it ----------
    us8 ra1[9], rb1[9];
    tap_loads(xpb1, o32_1, ra1, rb1);

    main_mfma_epilogue<BF16Y>(kw0, so, l, wv, g, r15, bfr, b_conv,
                              swz0, b0, h0, outf, yws, psum, psq);

    // row1 math + pack + main
    tap_math_pack(kw1, l, W00_1, W01_1, W10_1, W11_1, ra1, rb1);
    main_mfma_epilogue<BF16Y>(kw1, so, l, wv, g, r15, bfr, b_conv,
                              swz1, b1, h1, outf, yws, psum, psq);
}

// ---------------------------------------------------------------------------
// Kernel 2: reduce per-wave partials -> per-channel scale/shift
// ---------------------------------------------------------------------------
__global__ __launch_bounds__(256) void bn_stats_kernel(
    const float* __restrict__ psum,
    const float* __restrict__ psq,
    const float* __restrict__ gamma,
    const float* __restrict__ beta,
    float* __restrict__ ss)       // [0..63]=scale, [64..127]=shift
{
    __shared__ float rs[256], rq[256];
    const int ch = blockIdx.x, tid = threadIdx.x;
    float s = 0.f, s2 = 0.f;
    for (int j = tid; j < NBLKW; j += 256) {
        s  += psum[ch*NBLKW + j];
        s2 += psq [ch*NBLKW + j];
    }
    rs[tid] = s; rq[tid] = s2;
    __syncthreads();
    for (int st = 128; st > 0; st >>= 1) {
        if (tid < st) { rs[tid] += rs[tid + st]; rq[tid] += rq[tid + st]; }
        __syncthreads();
    }
    if (tid == 0) {
        const float N = (float)NPIX;
        float mean = rs[0] / N;
        float var  = rq[0] / N - mean*mean;
        float rstd = rsqrtf(var + 1e-5f);
        float sc   = gamma[ch] * rstd;
        ss[ch]      = sc;
        ss[64 + ch] = beta[ch] - mean * sc;
    }
}

// ---------------------------------------------------------------------------
// Kernel 3a (bf16 path): read y bf16 from ws, affine + SiLU, fp32 out
// ---------------------------------------------------------------------------
__global__ __launch_bounds__(256) void bn_silu_bf16_kernel(
    const unsigned short* __restrict__ yws,
    float* __restrict__ out,
    const float* __restrict__ ss)
{
    __shared__ float sc[64], sh[64];
    if (threadIdx.x < 64) {
        sc[threadIdx.x] = ss[threadIdx.x];
        sh[threadIdx.x] = ss[64 + threadIdx.x];
    }
    __syncthreads();
    const int total8 = (int)(YTOT / 8);
    for (int i = blockIdx.x*256 + threadIdx.x; i < total8; i += gridDim.x*256) {
        us8 v = *(const us8*)(yws + (size_t)i*8);
        const int o = (i >> 13) & 63;
        const float a = sc[o], t = sh[o];
        float e[8];
        #pragma unroll
        for (int j = 0; j < 8; ++j) {
            float z = fmaf(bf2f(v[j]), a, t);
            e[j] = z / (1.f + __expf(-z));
        }
        float4 r0 = { e[0], e[1], e[2], e[3] };
        float4 r1 = { e[4], e[5], e[6], e[7] };
        *(float4*)(out + (size_t)i*8)     = r0;
        *(float4*)(out + (size_t)i*8 + 4) = r1;
    }
}

// ---------------------------------------------------------------------------
// Kernel 3b (fallback): in-place affine + SiLU over fp32 d_out
// ---------------------------------------------------------------------------
__global__ __launch_bounds__(256) void bn_silu_kernel(
    float* __restrict__ y,
    const float* __restrict__ ss)
{
    __shared__ float sc[64], sh[64];
    if (threadIdx.x < 64) {
        sc[threadIdx.x] = ss[threadIdx.x];
        sh[threadIdx.x] = ss[64 + threadIdx.x];
    }
    __syncthreads();
    float4* y4 = (float4*)y;
    const int total4 = (int)(YTOT / 4);
    for (int i = blockIdx.x*256 + threadIdx.x; i < total4; i += gridDim.x*256) {
        float4 v = y4[i];
        const int o = (i >> 14) & 63;
        const float a = sc[o], t = sh[o];
        float z;
        z = fmaf(v.x, a, t); v.x = z / (1.f + __expf(-z));
        z = fmaf(v.y, a, t); v.y = z / (1.f + __expf(-z));
        z = fmaf(v.z, a, t); v.z = z / (1.f + __expf(-z));
        z = fmaf(v.w, a, t); v.w = z / (1.f + __expf(-z));
        y4[i] = v;
    }
}

// ---------------------------------------------------------------------------
extern "C" void kernel_launch(void* const* d_in, const int* in_sizes, int n_in,
                              void* d_out, int out_size, void* d_ws, size_t ws_size,
                              hipStream_t stream) {
    const float* x      = (const float*)d_in[0];
    const float* w_off  = (const float*)d_in[1];
    const float* b_off  = (const float*)d_in[2];
    const float* w_dcn  = (const float*)d_in[3];
    const float* w_conv = (const float*)d_in[4];
    const float* b_conv = (const float*)d_in[5];
    const float* gamma  = (const float*)d_in[6];
    const float* beta   = (const float*)d_in[7];
    float* out = (float*)d_out;

    const size_t yBytes    = YTOT * 2;                        // 128 MiB
    const size_t xpBytes   = (size_t)BB*PW*PW*8;              // 8.65 MB
    const size_t wtgBytes  = 8192 + 2048;                     // wTg + wOg
    const size_t statBytes = 2*(size_t)64*NBLKW*4 + 512;      // ~8.4 MB

    if (ws_size >= yBytes + xpBytes + wtgBytes + statBytes) {
        unsigned short* yws = (unsigned short*)d_ws;
        us4*            xpp = (us4*)((char*)d_ws + yBytes);
        unsigned short* wTg = (unsigned short*)((char*)d_ws + yBytes + xpBytes);
        unsigned short* wOg = wTg + 4096;
        float* psum = (float*)((char*)d_ws + yBytes + xpBytes + wtgBytes);
        float* psq  = psum + (size_t)64*NBLKW;
        float* ss   = psq  + (size_t)64*NBLKW;
        prep_kernel<<<BB*PW, 256, 0, stream>>>(x, xpp);
        wtg_kernel<<<1, 256, 0, stream>>>(w_dcn, w_conv, w_off, wTg, wOg);
        dcn_wave_kernel<true><<<NBLK2, 256, 0, stream>>>(
            xpp, wTg, wOg, b_off, b_conv, nullptr, yws, psum, psq);
        bn_stats_kernel<<<64, 256, 0, stream>>>(psum, psq, gamma, beta, ss);
        bn_silu_bf16_kernel<<<2048, 256, 0, stream>>>(yws, out, ss);
    } else {
        // fallback: fp32 y staged in d_out, normalized in place
        us4*            xpp = (us4*)d_ws;
        unsigned short* wTg = (unsigned short*)((char*)d_ws + xpBytes);
        unsigned short* wOg = wTg + 4096;
        float* psum = (float*)((char*)d_ws + xpBytes + wtgBytes);
        float* psq  = psum + (size_t)64*NBLKW;
        float* ss   = psq  + (size_t)64*NBLKW;
        prep_kernel<<<BB*PW, 256, 0, stream>>>(x, xpp);
        wtg_kernel<<<1, 256, 0, stream>>>(w_dcn, w_conv, w_off, wTg, wOg);
        dcn_wave_kernel<false><<<NBLK2, 256, 0, stream>>>(
            xpp, wTg, wOg, b_off, b_conv, out, nullptr, psum, psq);
        bn_stats_kernel<<<64, 256, 0, stream>>>(psum, psq, gamma, beta, ss);
        bn_silu_kernel<<<2048, 256, 0, stream>>>(out, ss);
    }
}